// Round 11
// baseline (119.165 us; speedup 1.0000x reference)
//
#include <hip/hip_runtime.h>

// StochaPolicy: out[b,0:32] = phi_m @ w_m.T + b_m ; out[b,32:64] = exp(clip(phi_s @ w_s.T + b_s))
// phi_h[b,k] = exp(-(|x|^2 - 2 x.C_h[k] + |C_h[k]|^2) / (2|sigma_h[k]|))
// B=32768 D=256 K=1024 A=32.
//
// R11: R10's coalesced-load K-loop (cf: 64-lane x 16B contiguous; wt: one
// dwordx4/pair) + R9's b-32 per-wave tiling for 3 waves/SIMD
// (__launch_bounds__(256,3), grid 1024). R9's occupancy test failed only
// because its loads were 64-line gathers (line pressure doubled); with R10
// coalescing the line stream is ~4x cheaper, so +50% TLP now buys latency
// hiding instead of queueing. Math bit-identical to R10.

typedef float floatx4 __attribute__((ext_vector_type(4)));
typedef int   intx4  __attribute__((ext_vector_type(4)));
typedef unsigned int u32;
typedef unsigned char u8;

constexpr float LOG2E = 1.4426950408889634f;
constexpr float QS    = 25.4f;                 // 127/5 quant multiplier
constexpr float SINV2 = (5.0f / 127.0f) * (5.0f / 127.0f);

__device__ __forceinline__ u32 pk_fp8(float a, float b, float c, float d) {
  u32 v = __builtin_amdgcn_cvt_pk_fp8_f32(a, b, 0u, 0);   // bytes 0,1
  v = __builtin_amdgcn_cvt_pk_fp8_f32(c, d, v, 1);        // bytes 2,3
  return v;
}
__device__ __forceinline__ long mk64(u32 lo, u32 hi) {
  return (long)lo | ((long)hi << 32);
}
__device__ __forceinline__ int q8(float x) {
  return (int)rintf(fminf(fmaxf(x * QS, -127.f), 127.f));
}
__device__ __forceinline__ u32 pk_i8(int a, int b, int c, int d) {
  return (u32)(a & 255) | ((u32)(b & 255) << 8) | ((u32)(c & 255) << 16) | ((u32)(d & 255) << 24);
}

// ---------- merged prologue (identical to R10) ----------
__global__ void prep(const float* __restrict__ mC, const float* __restrict__ mS,
                     const float* __restrict__ sC, const float* __restrict__ sS,
                     const float* __restrict__ mw, const float* __restrict__ sw,
                     u8* __restrict__ Cb2, float* __restrict__ a2g,
                     float* __restrict__ g2n, u8* __restrict__ wt)
{
  const int blk = blockIdx.x;
  if (blk < 512) {
    const int wq = threadIdx.x >> 6;
    const int t  = threadIdx.x & 63;
    const int b  = blk * 4 + wq;            // 0..2047 combined center index
    const int half = b >> 10;
    const int k = b & 1023;
    const float* src = (half ? sC : mC) + (size_t)k * 256;
    float4 f = *(const float4*)(src + t * 4);
    int i0 = q8(f.x), i1 = q8(f.y), i2 = q8(f.z), i3 = q8(f.w);
    const int ct = b >> 6, row = b & 63;
    const int wvv = row >> 4, cc = row & 15;
    const int ks = t >> 4, qq = (t >> 2) & 3, j0 = (t & 3) * 4;
    *(u32*)(Cb2 + (size_t)ct * 16384 + wvv * 4096 + (ks * 64 + qq * 16 + cc) * 16 + j0) =
        pk_i8(i0, i1, i2, i3);
    int is = i0 * i0 + i1 * i1 + i2 * i2 + i3 * i3;
    for (int off = 32; off > 0; off >>= 1) is += __shfl_down(is, off, 64);
    if (t == 0) {
      float sig = fabsf((half ? sS : mS)[k]);
      float t2 = SINV2 * LOG2E * 0.5f / sig;
      a2g[b] = 2.f * t2;
      g2n[b] = -t2 * (float)is;
    }
  } else {
    // wt builder: block = pair m, thread = tid of the main kernel
    const int m   = blk - 512;              // 0..15
    const int tid = threadIdx.x;
    const int wv  = tid >> 6;
    const int lane = tid & 63;
    const int c   = lane & 15;
    const int q   = lane >> 4;
    const int kbE = ((2 * m) & 15) * 64 + 16 * wv + 4 * q;
    const float* src = (m < 8) ? mw : sw;   // w_h[a][k], A=32 x K=1024
    float4 f00 = *(const float4*)(src + (size_t)c * 1024 + kbE);
    float4 f01 = *(const float4*)(src + (size_t)c * 1024 + kbE + 64);
    float4 f10 = *(const float4*)(src + (size_t)(16 + c) * 1024 + kbE);
    float4 f11 = *(const float4*)(src + (size_t)(16 + c) * 1024 + kbE + 64);
    uint4 o;
    o.x = pk_fp8(f00.x, f00.y, f00.z, f00.w);   // w0lo: even-tile K bytes
    o.y = pk_fp8(f01.x, f01.y, f01.z, f01.w);   // w0hi: odd-tile K bytes
    o.z = pk_fp8(f10.x, f10.y, f10.z, f10.w);   // w1lo
    o.w = pk_fp8(f11.x, f11.y, f11.z, f11.w);   // w1hi
    *(uint4*)(wt + ((size_t)m * 256 + tid) * 16) = o;
  }
}

// ---------- main fused kernel ----------
__global__ __launch_bounds__(256, 3)
void policy_main(const float* __restrict__ obs,
                 const u8* __restrict__ Cb2,
                 const float* __restrict__ a2g,
                 const float* __restrict__ g2n,
                 const u8* __restrict__ wt,
                 const float* __restrict__ mbias,
                 const float* __restrict__ sbias,
                 float* __restrict__ out)
{
  // LDS: prologue obs i8 tile [0,8192) + x2p [8192,10368).
  // Epilogue red[4][32][68] f32 (34816 B) aliases from 0.
  __shared__ __align__(16) char smem[34816];
  float* x2p = (float*)(smem + 8192);
  float* red = (float*)smem;

  const int tid  = threadIdx.x;
  const int lane = tid & 63;
  const int wv   = tid >> 6;        // wave 0..3 : kc slice [16wv,16wv+16)
  const int c    = lane & 15;
  const int q    = lane >> 4;       // quad 0..3
  const int row0 = blockIdx.x * 32; // 32 obs rows per block
  const int kslc = 16 * wv + 4 * q; // lane's kc sub-slice base within tile
  const int cfo  = wv * 4096 + lane * 16;  // coalesced fragment base
  const u8* wtl  = wt + (size_t)tid * 16;  // lane's wt column

  // chunk j of this lane's tile-fragment lives at cfo + j*1024 (coalesced)
#define LOADCF(CF, t)                                                     \
  { const u8* g0_ = Cb2 + (size_t)(t) * 16384 + cfo;                      \
    CF[0] = *(const intx4*)(g0_);                                         \
    CF[1] = *(const intx4*)(g0_ + 1024);                                  \
    CF[2] = *(const intx4*)(g0_ + 2048);                                  \
    CF[3] = *(const intx4*)(g0_ + 3072); }

  intx4 cfU[4], cfV[4];
  LOADCF(cfU, 0)
  LOADCF(cfV, 1)

  // ---- convert obs tile (32 rows) fp32 -> i8 into LDS (XOR-swizzled) + x2 ----
  #pragma unroll
  for (int i = 0; i < 2; ++i) {
    int s = i * 256 + tid;          // 16B slot 0..511
    int row = s >> 4;               // 0..31
    int s16 = s & 15;
    int l16 = s16 ^ (row & 15);
    const float* src = obs + (size_t)(row0 + row) * 256 + l16 * 16;
    float4 f0 = ((const float4*)src)[0];
    float4 f1 = ((const float4*)src)[1];
    float4 f2 = ((const float4*)src)[2];
    float4 f3 = ((const float4*)src)[3];
    int a0 = q8(f0.x), a1v = q8(f0.y), a2v = q8(f0.z), a3 = q8(f0.w);
    int b0 = q8(f1.x), b1 = q8(f1.y), b2 = q8(f1.z), b3 = q8(f1.w);
    int c0 = q8(f2.x), c1 = q8(f2.y), c2 = q8(f2.z), c3 = q8(f2.w);
    int d0 = q8(f3.x), d1 = q8(f3.y), d2 = q8(f3.z), d3 = q8(f3.w);
    uint4 pk;
    pk.x = pk_i8(a0, a1v, a2v, a3);
    pk.y = pk_i8(b0, b1, b2, b3);
    pk.z = pk_i8(c0, c1, c2, c3);
    pk.w = pk_i8(d0, d1, d2, d3);
    *(uint4*)(smem + s * 16) = pk;
    int is = a0*a0 + a1v*a1v + a2v*a2v + a3*a3
           + b0*b0 + b1*b1 + b2*b2 + b3*b3
           + c0*c0 + c1*c1 + c2*c2 + c3*c3
           + d0*d0 + d1*d1 + d2*d2 + d3*d3;
    x2p[row * 16 + s16] = (float)is;
  }
  __syncthreads();   // obs tile + partials visible

  // ---- preload obs B-fragments: ob[nt][ks] = obs[b=nt*16+c][d=64ks+16q..+16] ----
  intx4 ob[2][4];                   // 32 regs (MFMA operands)
  #pragma unroll
  for (int nt = 0; nt < 2; ++nt) {
    const int row = nt * 16 + c;
    #pragma unroll
    for (int ks = 0; ks < 4; ++ks) {
      int slot = (4 * ks + q) ^ (row & 15);
      ob[nt][ks] = *(const intx4*)(smem + row * 256 + slot * 16);
    }
  }
  if (tid < 32) {
    float s = 0.f;
    #pragma unroll
    for (int j = 0; j < 16; j += 4) {
      float4 a = *(const float4*)(x2p + tid * 16 + j);
      s += a.x + a.y + a.z + a.w;
    }
    x2p[512 + tid] = s;
  }
  __syncthreads();   // x2 sums visible (last barrier before epilogue)

  float hx2[2];
  #pragma unroll
  for (int nt = 0; nt < 2; ++nt) hx2[nt] = 0.5f * x2p[512 + nt * 16 + c];

  const intx4 Z4i = {0, 0, 0, 0};
  const floatx4 Z4 = {0.f, 0.f, 0.f, 0.f};
  floatx4 acc2m[2][2], acc2s[2][2];   // 32 regs (AGPR), static indexing only
  #pragma unroll
  for (int a2i = 0; a2i < 2; ++a2i)
    #pragma unroll
    for (int nt = 0; nt < 2; ++nt) {
      acc2m[a2i][nt] = Z4;
      acc2s[a2i][nt] = Z4;
    }

  intx4 a1A[2], a1B[2];
  float4 acA, gcA, acB, gcB;
  u32 pE[2], pc[2];

#define GEMM1T(CF, A1)                                                          \
  { A1[0] = __builtin_amdgcn_mfma_i32_16x16x64_i8(CF[0], ob[0][0], Z4i, 0, 0, 0); \
    A1[1] = __builtin_amdgcn_mfma_i32_16x16x64_i8(CF[0], ob[1][0], Z4i, 0, 0, 0); \
    _Pragma("unroll")                                                           \
    for (int ks = 1; ks < 4; ++ks) {                                            \
      A1[0] = __builtin_amdgcn_mfma_i32_16x16x64_i8(CF[ks], ob[0][ks], A1[0], 0, 0, 0); \
      A1[1] = __builtin_amdgcn_mfma_i32_16x16x64_i8(CF[ks], ob[1][ks], A1[1], 0, 0, 0); \
    } }

#define EXPP(A1, AC, GC, DST)                                                   \
  { _Pragma("unroll")                                                           \
    for (int nt = 0; nt < 2; ++nt) {                                            \
      float t0 = (float)A1[nt][0] - hx2[nt], t1 = (float)A1[nt][1] - hx2[nt];   \
      float t2 = (float)A1[nt][2] - hx2[nt], t3 = (float)A1[nt][3] - hx2[nt];   \
      DST[nt] = pk_fp8(__builtin_amdgcn_exp2f(fmaf(AC.x, t0, GC.x)),            \
                       __builtin_amdgcn_exp2f(fmaf(AC.y, t1, GC.y)),            \
                       __builtin_amdgcn_exp2f(fmaf(AC.z, t2, GC.z)),            \
                       __builtin_amdgcn_exp2f(fmaf(AC.w, t3, GC.w))); } }

#define GEMM2P(ACC, WV4)                                                        \
  { long wA0 = mk64(WV4.x, WV4.y), wA1 = mk64(WV4.z, WV4.w);                    \
    _Pragma("unroll")                                                           \
    for (int nt = 0; nt < 2; ++nt) {                                            \
      long pb = mk64(pE[nt], pc[nt]);                                           \
      ACC[0][nt] = __builtin_amdgcn_mfma_f32_16x16x32_fp8_fp8(wA0, pb, ACC[0][nt], 0, 0, 0); \
      ACC[1][nt] = __builtin_amdgcn_mfma_f32_16x16x32_fp8_fp8(wA1, pb, ACC[1][nt], 0, 0, 0); \
    } }

  // pipeline prologue: tile0 GEMM1 issued, cfU refilled with tile2
  acA = *(const float4*)(a2g + kslc);
  gcA = *(const float4*)(g2n + kslc);
  GEMM1T(cfU, a1A)
  LOADCF(cfU, 2)

  // STEP(m): GEMM1(2m+1) ; exp(2m) ; GEMM1(2m+2) ; exp(2m+1) ; GEMM2(pair m)
#define STEP(m, ACC, DO_U)                                                      \
  {                                                                             \
    const int e = 2 * (m);                                                      \
    uint4 wv4 = *(const uint4*)(wtl + (size_t)(m) * 4096);                      \
    acB = *(const float4*)(a2g + (e + 1) * 64 + kslc);                          \
    gcB = *(const float4*)(g2n + (e + 1) * 64 + kslc);                          \
    GEMM1T(cfV, a1B)                                                            \
    LOADCF(cfV, e + 3)                                                          \
    EXPP(a1A, acA, gcA, pE)                                                     \
    acA = *(const float4*)(a2g + (e + 2) * 64 + kslc);                          \
    gcA = *(const float4*)(g2n + (e + 2) * 64 + kslc);                          \
    GEMM1T(cfU, a1A)                                                            \
    if (DO_U) LOADCF(cfU, e + 4)                                                \
    EXPP(a1B, acB, gcB, pc)                                                     \
    GEMM2P(ACC, wv4)                                                            \
  }

  #pragma unroll
  for (int m = 0; m < 8; ++m) STEP(m, acc2m, 1)
  #pragma unroll
  for (int m = 8; m < 14; ++m) STEP(m, acc2s, 1)
  STEP(14, acc2s, 0)
  // last pair: tiles 30 (in a1A) and 31 (via cfV)
  {
    uint4 wv4 = *(const uint4*)(wtl + (size_t)15 * 4096);
    acB = *(const float4*)(a2g + 31 * 64 + kslc);
    gcB = *(const float4*)(g2n + 31 * 64 + kslc);
    GEMM1T(cfV, a1B)
    EXPP(a1A, acA, gcA, pE)
    EXPP(a1B, acB, gcB, pc)
    GEMM2P(acc2s, wv4)
  }
#undef STEP
#undef GEMM1T
#undef EXPP
#undef GEMM2P
#undef LOADCF

  // ---- epilogue: cross-wave reduction (red aliases obs LDS) ----
  // red[wv][bl=32][a=68pad]; lane(c,q) reg r holds a = h*32+a2i*16+4q+r, bl = nt*16+c
  {
    float* myr = red + wv * 2176;
    #pragma unroll
    for (int a2i = 0; a2i < 2; ++a2i)
      #pragma unroll
      for (int nt = 0; nt < 2; ++nt) {
        *(floatx4*)(myr + (nt * 16 + c) * 68 + a2i * 16 + 4 * q)      = acc2m[a2i][nt];
        *(floatx4*)(myr + (nt * 16 + c) * 68 + 32 + a2i * 16 + 4 * q) = acc2s[a2i][nt];
      }
  }
  __syncthreads();

  #pragma unroll
  for (int i = 0; i < 8; ++i) {
    int idx = tid + 256 * i;        // 0..2047
    int a = idx & 63;
    int b = idx >> 6;               // 0..31
    float v = red[b * 68 + a] + red[2176 + b * 68 + a] +
              red[4352 + b * 68 + a] + red[6528 + b * 68 + a];
    if (a < 32) {
      v += mbias[a];
    } else {
      v += sbias[a - 32];
      v = fminf(fmaxf(v, -20.f), 2.f);
      v = __builtin_amdgcn_exp2f(v * LOG2E);
    }
    out[(size_t)(row0 + b) * 64 + a] = v;
  }
}

extern "C" void kernel_launch(void* const* d_in, const int* in_sizes, int n_in,
                              void* d_out, int out_size, void* d_ws, size_t ws_size,
                              hipStream_t stream) {
  const float* obs = (const float*)d_in[0];
  const float* mC  = (const float*)d_in[1];
  const float* mS  = (const float*)d_in[2];
  const float* mW  = (const float*)d_in[3];
  const float* mB  = (const float*)d_in[4];
  const float* sC  = (const float*)d_in[5];
  const float* sS  = (const float*)d_in[6];
  const float* sW  = (const float*)d_in[7];
  const float* sB  = (const float*)d_in[8];
  float* out = (float*)d_out;

  // workspace: Cb2[2048*256] i8 (512KB) | a2g[2048] f32 | g2n[2048] f32 | wt[64KB]
  u8*    Cb2 = (u8*)d_ws;
  float* a2g = (float*)((char*)d_ws + 2048 * 256);
  float* g2n = a2g + 2048;
  u8*    wt  = (u8*)(g2n + 2048);

  prep<<<528, 256, 0, stream>>>(mC, mS, sC, sS, mW, sW, Cb2, a2g, g2n, wt);
  policy_main<<<1024, 256, 0, stream>>>(obs, Cb2, a2g, g2n, wt, mB, sB, out);
}

// Round 12
// 116.557 us; speedup vs baseline: 1.0224x; 1.0224x over previous
//
#include <hip/hip_runtime.h>

// StochaPolicy: out[b,0:32] = phi_m @ w_m.T + b_m ; out[b,32:64] = exp(clip(phi_s @ w_s.T + b_s))
// phi_h[b,k] = exp(-(|x|^2 - 2 x.C_h[k] + |C_h[k]|^2) / (2|sigma_h[k]|))
// B=32768 D=256 K=1024 A=32.
//
// R12: R10 base (b-64 per-wave tile, grid 512, coalesced cf/wt loads) with the
// pair's two GEMM1 tiles interleaved into ONE MFMA sequence with 8 independent
// accumulator chains (a1E[4] + a1O[4]). R11 vs R10 isolated the last untested
// stall source: MFMA dependent-issue (4-chain GEMM1 barely covers ~20cyc MFMA
// latency; R11's 2-chain version was worse at higher occupancy). 8 chains give
// ~40 cyc between dependent issues. Math bit-identical to R10.

typedef float floatx4 __attribute__((ext_vector_type(4)));
typedef int   intx4  __attribute__((ext_vector_type(4)));
typedef unsigned int u32;
typedef unsigned char u8;

constexpr float LOG2E = 1.4426950408889634f;
constexpr float QS    = 25.4f;                 // 127/5 quant multiplier
constexpr float SINV2 = (5.0f / 127.0f) * (5.0f / 127.0f);

__device__ __forceinline__ u32 pk_fp8(float a, float b, float c, float d) {
  u32 v = __builtin_amdgcn_cvt_pk_fp8_f32(a, b, 0u, 0);   // bytes 0,1
  v = __builtin_amdgcn_cvt_pk_fp8_f32(c, d, v, 1);        // bytes 2,3
  return v;
}
__device__ __forceinline__ long mk64(u32 lo, u32 hi) {
  return (long)lo | ((long)hi << 32);
}
__device__ __forceinline__ int q8(float x) {
  return (int)rintf(fminf(fmaxf(x * QS, -127.f), 127.f));
}
__device__ __forceinline__ u32 pk_i8(int a, int b, int c, int d) {
  return (u32)(a & 255) | ((u32)(b & 255) << 8) | ((u32)(c & 255) << 16) | ((u32)(d & 255) << 24);
}

// ---------- merged prologue (identical to R10) ----------
__global__ void prep(const float* __restrict__ mC, const float* __restrict__ mS,
                     const float* __restrict__ sC, const float* __restrict__ sS,
                     const float* __restrict__ mw, const float* __restrict__ sw,
                     u8* __restrict__ Cb2, float* __restrict__ a2g,
                     float* __restrict__ g2n, u8* __restrict__ wt)
{
  const int blk = blockIdx.x;
  if (blk < 512) {
    const int wq = threadIdx.x >> 6;
    const int t  = threadIdx.x & 63;
    const int b  = blk * 4 + wq;            // 0..2047 combined center index
    const int half = b >> 10;
    const int k = b & 1023;
    const float* src = (half ? sC : mC) + (size_t)k * 256;
    float4 f = *(const float4*)(src + t * 4);
    int i0 = q8(f.x), i1 = q8(f.y), i2 = q8(f.z), i3 = q8(f.w);
    const int ct = b >> 6, row = b & 63;
    const int wvv = row >> 4, cc = row & 15;
    const int ks = t >> 4, qq = (t >> 2) & 3, j0 = (t & 3) * 4;
    *(u32*)(Cb2 + (size_t)ct * 16384 + wvv * 4096 + (ks * 64 + qq * 16 + cc) * 16 + j0) =
        pk_i8(i0, i1, i2, i3);
    int is = i0 * i0 + i1 * i1 + i2 * i2 + i3 * i3;
    for (int off = 32; off > 0; off >>= 1) is += __shfl_down(is, off, 64);
    if (t == 0) {
      float sig = fabsf((half ? sS : mS)[k]);
      float t2 = SINV2 * LOG2E * 0.5f / sig;
      a2g[b] = 2.f * t2;
      g2n[b] = -t2 * (float)is;
    }
  } else {
    // wt builder: block = pair m, thread = tid of the main kernel
    const int m   = blk - 512;              // 0..15
    const int tid = threadIdx.x;
    const int wv  = tid >> 6;
    const int lane = tid & 63;
    const int c   = lane & 15;
    const int q   = lane >> 4;
    const int kbE = ((2 * m) & 15) * 64 + 16 * wv + 4 * q;
    const float* src = (m < 8) ? mw : sw;   // w_h[a][k], A=32 x K=1024
    float4 f00 = *(const float4*)(src + (size_t)c * 1024 + kbE);
    float4 f01 = *(const float4*)(src + (size_t)c * 1024 + kbE + 64);
    float4 f10 = *(const float4*)(src + (size_t)(16 + c) * 1024 + kbE);
    float4 f11 = *(const float4*)(src + (size_t)(16 + c) * 1024 + kbE + 64);
    uint4 o;
    o.x = pk_fp8(f00.x, f00.y, f00.z, f00.w);   // w0lo: even-tile K bytes
    o.y = pk_fp8(f01.x, f01.y, f01.z, f01.w);   // w0hi: odd-tile K bytes
    o.z = pk_fp8(f10.x, f10.y, f10.z, f10.w);   // w1lo
    o.w = pk_fp8(f11.x, f11.y, f11.z, f11.w);   // w1hi
    *(uint4*)(wt + ((size_t)m * 256 + tid) * 16) = o;
  }
}

// ---------- main fused kernel ----------
__global__ __launch_bounds__(256, 2)
void policy_main(const float* __restrict__ obs,
                 const u8* __restrict__ Cb2,
                 const float* __restrict__ a2g,
                 const float* __restrict__ g2n,
                 const u8* __restrict__ wt,
                 const float* __restrict__ mbias,
                 const float* __restrict__ sbias,
                 float* __restrict__ out)
{
  // LDS: prologue obs i8 tile [0,16384) + x2p [16384,20736).
  // Epilogue red[4][64][68] f32 (69632 B) aliases from 0.
  __shared__ __align__(16) char smem[69888];
  float* x2p = (float*)(smem + 16384);
  float* red = (float*)smem;

  const int tid  = threadIdx.x;
  const int lane = tid & 63;
  const int wv   = tid >> 6;        // wave 0..3 : kc slice [16wv,16wv+16)
  const int c    = lane & 15;
  const int q    = lane >> 4;       // quad 0..3
  const int row0 = blockIdx.x * 64;
  const int kslc = 16 * wv + 4 * q; // lane's kc sub-slice base within tile
  const int cfo  = wv * 4096 + lane * 16;  // coalesced fragment base
  const u8* wtl  = wt + (size_t)tid * 16;  // lane's wt column

  // chunk j of this lane's tile-fragment lives at cfo + j*1024 (coalesced)
#define LOADCF(CF, t)                                                     \
  { const u8* g0_ = Cb2 + (size_t)(t) * 16384 + cfo;                      \
    CF[0] = *(const intx4*)(g0_);                                         \
    CF[1] = *(const intx4*)(g0_ + 1024);                                  \
    CF[2] = *(const intx4*)(g0_ + 2048);                                  \
    CF[3] = *(const intx4*)(g0_ + 3072); }

  intx4 cfU[4], cfV[4];
  LOADCF(cfU, 0)
  LOADCF(cfV, 1)

  // ---- convert obs tile fp32 -> i8 into LDS (XOR-swizzled 16B slots) + x2 ----
  #pragma unroll
  for (int i = 0; i < 4; ++i) {
    int s = i * 256 + tid;          // 16B slot 0..1023
    int row = s >> 4;
    int s16 = s & 15;
    int l16 = s16 ^ (row & 15);
    const float* src = obs + (size_t)(row0 + row) * 256 + l16 * 16;
    float4 f0 = ((const float4*)src)[0];
    float4 f1 = ((const float4*)src)[1];
    float4 f2 = ((const float4*)src)[2];
    float4 f3 = ((const float4*)src)[3];
    int a0 = q8(f0.x), a1v = q8(f0.y), a2v = q8(f0.z), a3 = q8(f0.w);
    int b0 = q8(f1.x), b1 = q8(f1.y), b2 = q8(f1.z), b3 = q8(f1.w);
    int c0 = q8(f2.x), c1 = q8(f2.y), c2 = q8(f2.z), c3 = q8(f2.w);
    int d0 = q8(f3.x), d1 = q8(f3.y), d2 = q8(f3.z), d3 = q8(f3.w);
    uint4 pk;
    pk.x = pk_i8(a0, a1v, a2v, a3);
    pk.y = pk_i8(b0, b1, b2, b3);
    pk.z = pk_i8(c0, c1, c2, c3);
    pk.w = pk_i8(d0, d1, d2, d3);
    *(uint4*)(smem + s * 16) = pk;
    int is = a0*a0 + a1v*a1v + a2v*a2v + a3*a3
           + b0*b0 + b1*b1 + b2*b2 + b3*b3
           + c0*c0 + c1*c1 + c2*c2 + c3*c3
           + d0*d0 + d1*d1 + d2*d2 + d3*d3;
    x2p[row * 16 + s16] = (float)is;
  }
  __syncthreads();   // obs tile + partials visible

  // ---- preload obs B-fragments: ob[nt][ks] = obs[b=nt*16+c][d=64ks+16q..+16] ----
  intx4 ob[4][4];                   // 64 regs (MFMA operands)
  #pragma unroll
  for (int nt = 0; nt < 4; ++nt) {
    const int row = nt * 16 + c;
    #pragma unroll
    for (int ks = 0; ks < 4; ++ks) {
      int slot = (4 * ks + q) ^ (row & 15);
      ob[nt][ks] = *(const intx4*)(smem + row * 256 + slot * 16);
    }
  }
  if (tid < 64) {
    float s = 0.f;
    #pragma unroll
    for (int j = 0; j < 16; j += 4) {
      float4 a = *(const float4*)(x2p + tid * 16 + j);
      s += a.x + a.y + a.z + a.w;
    }
    x2p[1024 + tid] = s;
  }
  __syncthreads();   // x2 sums visible (last barrier before epilogue)

  float hx2[4];
  #pragma unroll
  for (int nt = 0; nt < 4; ++nt) hx2[nt] = 0.5f * x2p[1024 + nt * 16 + c];

  const intx4 Z4i = {0, 0, 0, 0};
  const floatx4 Z4 = {0.f, 0.f, 0.f, 0.f};
  floatx4 acc2m[2][4], acc2s[2][4];   // 64 regs (AGPR), static indexing only
  #pragma unroll
  for (int a2i = 0; a2i < 2; ++a2i)
    #pragma unroll
    for (int nt = 0; nt < 4; ++nt) {
      acc2m[a2i][nt] = Z4;
      acc2s[a2i][nt] = Z4;
    }

  intx4 a1E[4], a1O[4];             // 8 independent accumulator chains
  u32 pE[4], pc[4];

  // interleaved GEMM1 for BOTH tiles of a pair: 8 chains, dep distance = 8 issues
#define GEMM1PAIR()                                                             \
  { _Pragma("unroll")                                                           \
    for (int nt = 0; nt < 4; ++nt) {                                            \
      a1E[nt] = __builtin_amdgcn_mfma_i32_16x16x64_i8(cfU[0], ob[nt][0], Z4i, 0, 0, 0); \
      a1O[nt] = __builtin_amdgcn_mfma_i32_16x16x64_i8(cfV[0], ob[nt][0], Z4i, 0, 0, 0); \
    }                                                                           \
    _Pragma("unroll")                                                           \
    for (int ks = 1; ks < 4; ++ks) {                                            \
      _Pragma("unroll")                                                         \
      for (int nt = 0; nt < 4; ++nt) {                                          \
        a1E[nt] = __builtin_amdgcn_mfma_i32_16x16x64_i8(cfU[ks], ob[nt][ks], a1E[nt], 0, 0, 0); \
        a1O[nt] = __builtin_amdgcn_mfma_i32_16x16x64_i8(cfV[ks], ob[nt][ks], a1O[nt], 0, 0, 0); \
      }                                                                         \
    } }

#define EXPP(A1, AC, GC, DST)                                                   \
  { _Pragma("unroll")                                                           \
    for (int nt = 0; nt < 4; ++nt) {                                            \
      float t0 = (float)A1[nt][0] - hx2[nt], t1 = (float)A1[nt][1] - hx2[nt];   \
      float t2 = (float)A1[nt][2] - hx2[nt], t3 = (float)A1[nt][3] - hx2[nt];   \
      DST[nt] = pk_fp8(__builtin_amdgcn_exp2f(fmaf(AC.x, t0, GC.x)),            \
                       __builtin_amdgcn_exp2f(fmaf(AC.y, t1, GC.y)),            \
                       __builtin_amdgcn_exp2f(fmaf(AC.z, t2, GC.z)),            \
                       __builtin_amdgcn_exp2f(fmaf(AC.w, t3, GC.w))); } }

#define GEMM2P(ACC, WV4)                                                        \
  { long wA0 = mk64(WV4.x, WV4.y), wA1 = mk64(WV4.z, WV4.w);                    \
    _Pragma("unroll")                                                           \
    for (int nt = 0; nt < 4; ++nt) {                                            \
      long pb = mk64(pE[nt], pc[nt]);                                           \
      ACC[0][nt] = __builtin_amdgcn_mfma_f32_16x16x32_fp8_fp8(wA0, pb, ACC[0][nt], 0, 0, 0); \
      ACC[1][nt] = __builtin_amdgcn_mfma_f32_16x16x32_fp8_fp8(wA1, pb, ACC[1][nt], 0, 0, 0); \
    } }

  // STEP(m): GEMM1(both tiles, interleaved) ; prefetch pair m+1 ; exp both ; GEMM2
#define STEP(m, ACC, PF)                                                        \
  {                                                                             \
    const int e = 2 * (m);                                                      \
    uint4 wv4 = *(const uint4*)(wtl + (size_t)(m) * 4096);                      \
    float4 acE = *(const float4*)(a2g + e * 64 + kslc);                         \
    float4 gcE = *(const float4*)(g2n + e * 64 + kslc);                         \
    float4 acO = *(const float4*)(a2g + (e + 1) * 64 + kslc);                   \
    float4 gcO = *(const float4*)(g2n + (e + 1) * 64 + kslc);                   \
    GEMM1PAIR()                                                                 \
    if (PF) { LOADCF(cfU, e + 2) LOADCF(cfV, e + 3) }                           \
    EXPP(a1E, acE, gcE, pE)                                                     \
    EXPP(a1O, acO, gcO, pc)                                                     \
    GEMM2P(ACC, wv4)                                                            \
  }

  #pragma unroll
  for (int m = 0; m < 8; ++m) STEP(m, acc2m, 1)
  #pragma unroll
  for (int m = 8; m < 15; ++m) STEP(m, acc2s, 1)
  STEP(15, acc2s, 0)
#undef STEP
#undef GEMM1PAIR
#undef EXPP
#undef GEMM2P
#undef LOADCF

  // ---- epilogue: cross-wave reduction (red aliases obs LDS; K-loop reads no LDS) ----
  // red[wv][b=64][a=68pad]; lane(c,q) reg r holds a = h*32+a2i*16+4q+r, b = nt*16+c
  {
    float* myr = red + wv * 4352;
    #pragma unroll
    for (int a2i = 0; a2i < 2; ++a2i)
      #pragma unroll
      for (int nt = 0; nt < 4; ++nt) {
        *(floatx4*)(myr + (nt * 16 + c) * 68 + a2i * 16 + 4 * q)      = acc2m[a2i][nt];
        *(floatx4*)(myr + (nt * 16 + c) * 68 + 32 + a2i * 16 + 4 * q) = acc2s[a2i][nt];
      }
  }
  __syncthreads();

  #pragma unroll
  for (int i = 0; i < 16; ++i) {
    int idx = tid + 256 * i;        // 0..4095
    int a = idx & 63;
    int b = idx >> 6;
    float v = red[b * 68 + a] + red[4352 + b * 68 + a] +
              red[8704 + b * 68 + a] + red[13056 + b * 68 + a];
    if (a < 32) {
      v += mbias[a];
    } else {
      v += sbias[a - 32];
      v = fminf(fmaxf(v, -20.f), 2.f);
      v = __builtin_amdgcn_exp2f(v * LOG2E);
    }
    out[(size_t)(row0 + b) * 64 + a] = v;
  }
}

extern "C" void kernel_launch(void* const* d_in, const int* in_sizes, int n_in,
                              void* d_out, int out_size, void* d_ws, size_t ws_size,
                              hipStream_t stream) {
  const float* obs = (const float*)d_in[0];
  const float* mC  = (const float*)d_in[1];
  const float* mS  = (const float*)d_in[2];
  const float* mW  = (const float*)d_in[3];
  const float* mB  = (const float*)d_in[4];
  const float* sC  = (const float*)d_in[5];
  const float* sS  = (const float*)d_in[6];
  const float* sW  = (const float*)d_in[7];
  const float* sB  = (const float*)d_in[8];
  float* out = (float*)d_out;

  // workspace: Cb2[2048*256] i8 (512KB) | a2g[2048] f32 | g2n[2048] f32 | wt[64KB]
  u8*    Cb2 = (u8*)d_ws;
  float* a2g = (float*)((char*)d_ws + 2048 * 256);
  float* g2n = a2g + 2048;
  u8*    wt  = (u8*)(g2n + 2048);

  prep<<<528, 256, 0, stream>>>(mC, mS, sC, sS, mW, sW, Cb2, a2g, g2n, wt);
  policy_main<<<512, 256, 0, stream>>>(obs, Cb2, a2g, g2n, wt, mB, sB, out);
}